// Round 6
// baseline (206.692 us; speedup 1.0000x reference)
//
#include <hip/hip_runtime.h>
#include <math.h>

// Problem constants
constexpr int B_ = 8;
constexpr int N_ = 400;
constexpr int D_ = 768;
constexpr int M_ = 160;                 // int(0.4 * 400)
constexpr int PAIRS_ = M_ * (M_ - 1);   // 25440
constexpr size_t BMD_ = (size_t)B_ * M_ * D_;  // 983,040 (rank-dense)
constexpr int NBLK_ = 256;              // 1 block/CU; all co-resident (8x margin)
constexpr int NWAVE_ = NBLK_ * 4;       // 1024 waves

typedef __attribute__((ext_vector_type(8))) short short8;   // 8 bf16 (4 VGPRs)
typedef __attribute__((ext_vector_type(4))) float floatx4;  // MFMA C/D

// Workspace layout (bytes):
//   z     : double[B_*N_]     @ 0
//   pos   : int[B_*M_]        @ 25600
//   aterm : float[B_*M_*3]    @ 30720   (includes b_pair)
//   bterm : float[B_*M_*3]    @ 46080
//   rr    : int[B_*M_*2]      @ 61440   (span_ranges gathered by rank)
//   Xh    : short[BMD_]       @ 71680
//   Xl    : short[BMD_]       @ 2037760
//   Yh    : short[3][BMD_]    @ 4003840
//   Yl    : short[3][BMD_]    @ 9902080
//   bar   : unsigned[16]      @ 15900672  (memset to 0 before launch)

// ---------------------------------------------------------------------------
// Device-scope sense-reversing grid barrier. bar[0]=arrive, bar[1]=generation.
// __syncthreads drains every wave's stores to L2 (compiler emits vmcnt(0));
// __threadfence = agent-scope fence (L2 writeback on gfx950); acquire atomics
// invalidate, so plain data written before the barrier is visible after it.
__device__ __forceinline__ void grid_sync(unsigned* bar) {
  __syncthreads();
  if (threadIdx.x == 0) {
    __threadfence();
    unsigned gen = __hip_atomic_load(bar + 1, __ATOMIC_RELAXED, __HIP_MEMORY_SCOPE_AGENT);
    unsigned t = __hip_atomic_fetch_add(bar, 1u, __ATOMIC_ACQ_REL, __HIP_MEMORY_SCOPE_AGENT);
    if (t == (unsigned)NBLK_ - 1) {
      __hip_atomic_store(bar, 0u, __ATOMIC_RELAXED, __HIP_MEMORY_SCOPE_AGENT);
      __hip_atomic_fetch_add(bar + 1, 1u, __ATOMIC_ACQ_REL, __HIP_MEMORY_SCOPE_AGENT);
    } else {
      while (__hip_atomic_load(bar + 1, __ATOMIC_ACQUIRE, __HIP_MEMORY_SCOPE_AGENT) == gen)
        __builtin_amdgcn_s_sleep(2);
    }
    __threadfence();
  }
  __syncthreads();
}

// ---------------------------------------------------------------------------
// One persistent kernel, 4 phases separated by grid barriers.
__global__ __launch_bounds__(256) void k_fused(const float* __restrict__ x,
                                               const float* __restrict__ w_span,
                                               const float* __restrict__ w_pair,
                                               const float* __restrict__ b_pair,
                                               const int* __restrict__ span_ranges,
                                               double* __restrict__ z,
                                               int* __restrict__ pos,
                                               float* __restrict__ aterm,
                                               float* __restrict__ bterm,
                                               int* __restrict__ rr,
                                               short* __restrict__ Xh,
                                               short* __restrict__ Xl,
                                               short* __restrict__ Yh,
                                               short* __restrict__ Yl,
                                               unsigned* bar,
                                               float* __restrict__ out_probs,
                                               float4* __restrict__ out_ranges) {
  int lane = threadIdx.x & 63;
  int gw = blockIdx.x * 4 + (threadIdx.x >> 6);  // global wave id 0..1023
  const float* w3 = w_pair + 2 * D_ * 3;

  // ---- Phase A: z[row] = fp64 dot(x_row, w_span), all B*N rows ----
  for (int row = gw; row < B_ * N_; row += NWAVE_) {
    const float* xr = x + (size_t)row * D_;
    double acc = 0.0;
#pragma unroll
    for (int it = 0; it < 3; ++it) {
      int d = it * 256 + lane * 4;
      float4 xv = *(const float4*)(xr + d);
      float4 wv = *(const float4*)(w_span + d);
      acc += (double)xv.x * wv.x + (double)xv.y * wv.y +
             (double)xv.z * wv.z + (double)xv.w * wv.w;
    }
#pragma unroll
    for (int off = 32; off > 0; off >>= 1)
      acc += __shfl_down(acc, off, 64);
    if (lane == 0) z[row] = acc;
  }
  grid_sync(bar);

  // ---- Phase B: rank + sort (block b < 8 handles batch b) ----
  {
    __shared__ double zsh[N_];
    __shared__ int ranksh[M_];
    int b = blockIdx.x;
    int t = threadIdx.x;
    if (b < B_) {
      for (int j = t; j < N_; j += 256) zsh[j] = z[b * N_ + j];
      __syncthreads();
      if (t < M_) {
        double zi = zsh[t];
        int cnt = 0;
        for (int j = 0; j < N_; ++j) {
          double zj = zsh[j];
          cnt += (zj > zi) || (zj == zi && j < t);
        }
        ranksh[t] = cnt;
      }
      __syncthreads();
      if (t < M_) {
        int r = ranksh[t];
        int slot = 0;
#pragma unroll 8
        for (int k = 0; k < M_; ++k) slot += (ranksh[k] < r);
        pos[b * M_ + slot] = r;  // ranks distinct -> ascending sort
      }
    }
  }
  grid_sync(bar);

  // ---- Phase C: prep ranked rows (one wave per rank slot, B*M=1280) ----
  for (int s = gw; s < B_ * M_; s += NWAVE_) {
    int b = s / M_;
    int row = pos[s];
    const float* xr = x + ((size_t)(b * N_ + row)) * D_;
    float a0 = 0, a1 = 0, a2 = 0, c0 = 0, c1 = 0, c2 = 0;
#pragma unroll
    for (int it = 0; it < 3; ++it) {
      int d = it * 256 + lane * 4;
      float4 xv = *(const float4*)(xr + d);
      float xf[4] = {xv.x, xv.y, xv.z, xv.w};
      float w1v[12], w2v[12], w3v[12];
#pragma unroll
      for (int q = 0; q < 3; ++q) {
        *(float4*)(w1v + 4 * q) = *(const float4*)(w_pair + (size_t)d * 3 + 4 * q);
        *(float4*)(w2v + 4 * q) = *(const float4*)(w_pair + (size_t)(D_ + d) * 3 + 4 * q);
        *(float4*)(w3v + 4 * q) = *(const float4*)(w3 + (size_t)d * 3 + 4 * q);
      }
#pragma unroll
      for (int e = 0; e < 4; ++e) {
        a0 += xf[e] * w1v[e * 3 + 0];
        a1 += xf[e] * w1v[e * 3 + 1];
        a2 += xf[e] * w1v[e * 3 + 2];
        c0 += xf[e] * w2v[e * 3 + 0];
        c1 += xf[e] * w2v[e * 3 + 1];
        c2 += xf[e] * w2v[e * 3 + 2];
      }
      size_t o = (size_t)s * D_ + d;
      short xh[4], xl[4];
#pragma unroll
      for (int e = 0; e < 4; ++e) {
        unsigned h = __float_as_uint(xf[e]) & 0xffff0000u;
        xh[e] = (short)(h >> 16);
        xl[e] = (short)(__float_as_uint(xf[e] - __uint_as_float(h)) >> 16);
      }
      *(short4*)(Xh + o) = make_short4(xh[0], xh[1], xh[2], xh[3]);
      *(short4*)(Xl + o) = make_short4(xl[0], xl[1], xl[2], xl[3]);
#pragma unroll
      for (int c = 0; c < 3; ++c) {
        short yh[4], yl[4];
#pragma unroll
        for (int e = 0; e < 4; ++e) {
          float y = xf[e] * w3v[e * 3 + c];
          unsigned h = __float_as_uint(y) & 0xffff0000u;
          yh[e] = (short)(h >> 16);
          yl[e] = (short)(__float_as_uint(y - __uint_as_float(h)) >> 16);
        }
        *(short4*)(Yh + (size_t)c * BMD_ + o) = make_short4(yh[0], yh[1], yh[2], yh[3]);
        *(short4*)(Yl + (size_t)c * BMD_ + o) = make_short4(yl[0], yl[1], yl[2], yl[3]);
      }
    }
#pragma unroll
    for (int off = 32; off > 0; off >>= 1) {
      a0 += __shfl_down(a0, off, 64);
      a1 += __shfl_down(a1, off, 64);
      a2 += __shfl_down(a2, off, 64);
      c0 += __shfl_down(c0, off, 64);
      c1 += __shfl_down(c1, off, 64);
      c2 += __shfl_down(c2, off, 64);
    }
    if (lane == 0) {
      aterm[s * 3 + 0] = a0 + b_pair[0];
      aterm[s * 3 + 1] = a1 + b_pair[1];
      aterm[s * 3 + 2] = a2 + b_pair[2];
      bterm[s * 3 + 0] = c0;
      bterm[s * 3 + 1] = c1;
      bterm[s * 3 + 2] = c2;
      *(int2*)(rr + s * 2) = *(const int2*)(span_ranges + row * 2);
    }
  }
  grid_sync(bar);

  // ---- Phase D: MFMA pairs (one wave per (b, 16x16 tile); 800 tiles) ----
  if (gw < B_ * 100) {
    int b = gw / 100;
    int t = gw - b * 100;
    int ti = t / 10;            // i-tile (rows; A side = Y)
    int tj = t - ti * 10;       // j-tile (cols; B side = X)
    int quad = lane >> 4;
    int l16 = lane & 15;

    size_t oa = ((size_t)(b * M_ + ti * 16 + l16)) * D_ + quad * 8;
    size_t ob = ((size_t)(b * M_ + tj * 16 + l16)) * D_ + quad * 8;

    const short* ah0 = Yh + 0 * BMD_ + oa;
    const short* ah1 = Yh + 1 * BMD_ + oa;
    const short* ah2 = Yh + 2 * BMD_ + oa;
    const short* al0 = Yl + 0 * BMD_ + oa;
    const short* al1 = Yl + 1 * BMD_ + oa;
    const short* al2 = Yl + 2 * BMD_ + oa;
    const short* bhp = Xh + ob;
    const short* blp = Xl + ob;

    floatx4 acc0 = {0.f, 0.f, 0.f, 0.f};
    floatx4 acc1 = {0.f, 0.f, 0.f, 0.f};
    floatx4 acc2 = {0.f, 0.f, 0.f, 0.f};

#pragma unroll 4
    for (int k = 0; k < D_; k += 32) {
      short8 bh = *(const short8*)(bhp + k);
      short8 bl = *(const short8*)(blp + k);
      short8 h0 = *(const short8*)(ah0 + k);
      short8 l0 = *(const short8*)(al0 + k);
      short8 h1 = *(const short8*)(ah1 + k);
      short8 l1 = *(const short8*)(al1 + k);
      short8 h2 = *(const short8*)(ah2 + k);
      short8 l2 = *(const short8*)(al2 + k);

      acc0 = __builtin_amdgcn_mfma_f32_16x16x32_bf16(h0, bh, acc0, 0, 0, 0);
      acc0 = __builtin_amdgcn_mfma_f32_16x16x32_bf16(h0, bl, acc0, 0, 0, 0);
      acc0 = __builtin_amdgcn_mfma_f32_16x16x32_bf16(l0, bh, acc0, 0, 0, 0);
      acc1 = __builtin_amdgcn_mfma_f32_16x16x32_bf16(h1, bh, acc1, 0, 0, 0);
      acc1 = __builtin_amdgcn_mfma_f32_16x16x32_bf16(h1, bl, acc1, 0, 0, 0);
      acc1 = __builtin_amdgcn_mfma_f32_16x16x32_bf16(l1, bh, acc1, 0, 0, 0);
      acc2 = __builtin_amdgcn_mfma_f32_16x16x32_bf16(h2, bh, acc2, 0, 0, 0);
      acc2 = __builtin_amdgcn_mfma_f32_16x16x32_bf16(h2, bl, acc2, 0, 0, 0);
      acc2 = __builtin_amdgcn_mfma_f32_16x16x32_bf16(l2, bh, acc2, 0, 0, 0);
    }

    // Epilogue. C/D layout: col = lane&15 (j), row = quad*4 + reg (i).
    const float* at = aterm + (size_t)(b * M_) * 3;
    const float* bt = bterm + (size_t)(b * M_) * 3;
    const int* rrb = rr + (size_t)(b * M_) * 2;
    int j = tj * 16 + l16;
    float bj0 = bt[j * 3 + 0], bj1 = bt[j * 3 + 1], bj2 = bt[j * 3 + 2];
    int rj0 = rrb[j * 2 + 0], rj1 = rrb[j * 2 + 1];

#pragma unroll
    for (int r = 0; r < 4; ++r) {
      int i = ti * 16 + quad * 4 + r;
      if (i == j) continue;
      float l0 = acc0[r] + at[i * 3 + 0] + bj0;
      float l1 = acc1[r] + at[i * 3 + 1] + bj1;
      float l2 = acc2[r] + at[i * 3 + 2] + bj2;
      float s0 = 1.0f / (1.0f + expf(-l0));
      float s1 = 1.0f / (1.0f + expf(-l1));
      float s2 = 1.0f / (1.0f + expf(-l2));
      float e0 = expf(s0), e1 = expf(s1), e2 = expf(s2);
      float inv = 1.0f / (e0 + e1 + e2);
      int jj = j - (j > i ? 1 : 0);
      size_t p = (size_t)b * PAIRS_ + (size_t)i * (M_ - 1) + jj;
      out_probs[p * 3 + 0] = e0 * inv;
      out_probs[p * 3 + 1] = e1 * inv;
      out_probs[p * 3 + 2] = e2 * inv;
      float4 rg;
      rg.x = (float)rrb[i * 2 + 0];
      rg.y = (float)rrb[i * 2 + 1];
      rg.z = (float)rj0;
      rg.w = (float)rj1;
      out_ranges[p] = rg;
    }
  }
}

// ---------------------------------------------------------------------------
extern "C" void kernel_launch(void* const* d_in, const int* in_sizes, int n_in,
                              void* d_out, int out_size, void* d_ws, size_t ws_size,
                              hipStream_t stream) {
  const float* x = (const float*)d_in[0];
  const float* w_span = (const float*)d_in[1];
  // d_in[2] = b_span: constant shift, irrelevant to the ranking -> unused.
  const float* w_pair = (const float*)d_in[3];
  const float* b_pair = (const float*)d_in[4];
  const int* span_ranges = (const int*)d_in[5];

  char* ws = (char*)d_ws;
  double* z = (double*)ws;
  int* pos = (int*)(ws + 25600);
  float* aterm = (float*)(ws + 30720);
  float* bterm = (float*)(ws + 46080);
  int* rr = (int*)(ws + 61440);
  short* Xh = (short*)(ws + 71680);
  short* Xl = (short*)(ws + 2037760);
  short* Yh = (short*)(ws + 4003840);
  short* Yl = (short*)(ws + 9902080);
  unsigned* bar = (unsigned*)(ws + 15900672);

  float* out = (float*)d_out;
  float* out_probs = out;                                         // B*P*3 floats
  float4* out_ranges = (float4*)(out + (size_t)B_ * PAIRS_ * 3);  // B*P*4 floats

  // Barrier state must be zero at kernel start (ws is poisoned 0xAA).
  hipMemsetAsync(bar, 0, 64, stream);
  k_fused<<<NBLK_, 256, 0, stream>>>(x, w_span, w_pair, b_pair, span_ranges,
                                     z, pos, aterm, bterm, rr, Xh, Xl, Yh, Yl,
                                     bar, out_probs, out_ranges);
}

// Round 7
// 106.170 us; speedup vs baseline: 1.9468x; 1.9468x over previous
//
#include <hip/hip_runtime.h>
#include <math.h>

// Problem constants
constexpr int B_ = 8;
constexpr int N_ = 400;
constexpr int D_ = 768;
constexpr int M_ = 160;                 // int(0.4 * 400)
constexpr int PAIRS_ = M_ * (M_ - 1);   // 25440
constexpr size_t BMD_ = (size_t)B_ * M_ * D_;  // 983,040 (rank-dense)

typedef __attribute__((ext_vector_type(8))) short short8;   // 8 bf16 (4 VGPRs)
typedef __attribute__((ext_vector_type(4))) float floatx4;  // MFMA C/D

// Workspace layout (bytes), ~8 MB, all rank-dense:
//   z     : double[B_*N_]     @ 0
//   pos   : int[B_*M_]        @ 25600
//   aterm : float[B_*M_*3]    @ 30720   (includes b_pair)
//   bterm : float[B_*M_*3]    @ 46080
//   rr    : int[B_*M_*2]      @ 61440   (span_ranges gathered by rank)
//   Xbf   : short[BMD_]       @ 71680   (bf16 RNE of x, ranked rows)
//   Ybf   : short[3][BMD_]    @ 2037760 (bf16 RNE of x*w3_c, ranked rows)

// bf16 round-to-nearest-even (inputs are finite; NaN path not needed)
__device__ __forceinline__ short f2bf(float f) {
  unsigned u = __float_as_uint(f);
  return (short)((u + 0x7fffu + ((u >> 16) & 1u)) >> 16);
}

// ---------------------------------------------------------------------------
// Kernel 1: z[row] = fp64 dot(x_row, w_span). One wave per row (all B*N).
// Sigmoid is monotonic -> rank on z.
__global__ __launch_bounds__(256) void k_span(const float* __restrict__ x,
                                              const float* __restrict__ w_span,
                                              double* __restrict__ z) {
  int row = blockIdx.x * 4 + (threadIdx.x >> 6);
  int lane = threadIdx.x & 63;
  const float* xr = x + (size_t)row * D_;
  double acc = 0.0;
#pragma unroll
  for (int it = 0; it < 3; ++it) {
    int d = it * 256 + lane * 4;
    float4 xv = *(const float4*)(xr + d);
    float4 wv = *(const float4*)(w_span + d);
    acc += (double)xv.x * wv.x + (double)xv.y * wv.y +
           (double)xv.z * wv.z + (double)xv.w * wv.w;
  }
#pragma unroll
  for (int off = 32; off > 0; off >>= 1)
    acc += __shfl_down(acc, off, 64);
  if (lane == 0) z[row] = acc;
}

// ---------------------------------------------------------------------------
// Kernel 2: per batch, rank[i] (i<M) = stable descending rank of z[i];
// pos = sorted ascending of those ranks. One block per batch (tiny).
__global__ __launch_bounds__(256) void k_rank(const double* __restrict__ z,
                                              int* __restrict__ pos) {
  __shared__ double zsh[N_];
  __shared__ int ranksh[M_];
  int b = blockIdx.x;
  int t = threadIdx.x;
  for (int j = t; j < N_; j += 256) zsh[j] = z[b * N_ + j];
  __syncthreads();
  if (t < M_) {
    double zi = zsh[t];
    int cnt = 0;
    for (int j = 0; j < N_; ++j) {
      double zj = zsh[j];
      cnt += (zj > zi) || (zj == zi && j < t);
    }
    ranksh[t] = cnt;
  }
  __syncthreads();
  if (t < M_) {
    int r = ranksh[t];
    int slot = 0;
#pragma unroll 8
    for (int k = 0; k < M_; ++k) slot += (ranksh[k] < r);
    pos[b * M_ + slot] = r;  // ranks distinct -> ascending sort
  }
}

// ---------------------------------------------------------------------------
// Kernel 3 (prep, ranked rows only): one wave per rank slot (B*M = 1280).
// Per slot s = b*M+i with source row pos[s]:
//   aterm[s,c] = dot(x, w1[:,c]) + b_pair[c];  bterm[s,c] = dot(x, w2[:,c])
//   Xbf[s]  = bf16(x);  Ybf[c][s] = bf16(x * w3[:,c]);  rr[s] = ranges[pos[s]]
__global__ __launch_bounds__(256) void k_prep_ranked(const float* __restrict__ x,
                                                     const float* __restrict__ w_pair,
                                                     const float* __restrict__ b_pair,
                                                     const int* __restrict__ pos,
                                                     const int* __restrict__ span_ranges,
                                                     float* __restrict__ aterm,
                                                     float* __restrict__ bterm,
                                                     int* __restrict__ rr,
                                                     short* __restrict__ Xbf,
                                                     short* __restrict__ Ybf) {
  int s = blockIdx.x * 4 + (threadIdx.x >> 6);  // rank slot: b*M_ + i
  int lane = threadIdx.x & 63;
  int b = s / M_;
  int row = pos[s];
  const float* xr = x + ((size_t)(b * N_ + row)) * D_;
  const float* w3 = w_pair + 2 * D_ * 3;

  float a0 = 0, a1 = 0, a2 = 0, c0 = 0, c1 = 0, c2 = 0;
#pragma unroll
  for (int it = 0; it < 3; ++it) {
    int d = it * 256 + lane * 4;
    float4 xv = *(const float4*)(xr + d);
    float xf[4] = {xv.x, xv.y, xv.z, xv.w};

    float w1v[12], w2v[12], w3v[12];
#pragma unroll
    for (int q = 0; q < 3; ++q) {
      *(float4*)(w1v + 4 * q) = *(const float4*)(w_pair + (size_t)d * 3 + 4 * q);
      *(float4*)(w2v + 4 * q) = *(const float4*)(w_pair + (size_t)(D_ + d) * 3 + 4 * q);
      *(float4*)(w3v + 4 * q) = *(const float4*)(w3 + (size_t)d * 3 + 4 * q);
    }
#pragma unroll
    for (int e = 0; e < 4; ++e) {
      a0 += xf[e] * w1v[e * 3 + 0];
      a1 += xf[e] * w1v[e * 3 + 1];
      a2 += xf[e] * w1v[e * 3 + 2];
      c0 += xf[e] * w2v[e * 3 + 0];
      c1 += xf[e] * w2v[e * 3 + 1];
      c2 += xf[e] * w2v[e * 3 + 2];
    }

    size_t o = (size_t)s * D_ + d;
    *(short4*)(Xbf + o) = make_short4(f2bf(xf[0]), f2bf(xf[1]), f2bf(xf[2]), f2bf(xf[3]));
#pragma unroll
    for (int c = 0; c < 3; ++c) {
      *(short4*)(Ybf + (size_t)c * BMD_ + o) =
          make_short4(f2bf(xf[0] * w3v[0 * 3 + c]), f2bf(xf[1] * w3v[1 * 3 + c]),
                      f2bf(xf[2] * w3v[2 * 3 + c]), f2bf(xf[3] * w3v[3 * 3 + c]));
    }
  }
#pragma unroll
  for (int off = 32; off > 0; off >>= 1) {
    a0 += __shfl_down(a0, off, 64);
    a1 += __shfl_down(a1, off, 64);
    a2 += __shfl_down(a2, off, 64);
    c0 += __shfl_down(c0, off, 64);
    c1 += __shfl_down(c1, off, 64);
    c2 += __shfl_down(c2, off, 64);
  }
  if (lane == 0) {
    aterm[s * 3 + 0] = a0 + b_pair[0];
    aterm[s * 3 + 1] = a1 + b_pair[1];
    aterm[s * 3 + 2] = a2 + b_pair[2];
    bterm[s * 3 + 0] = c0;
    bterm[s * 3 + 1] = c1;
    bterm[s * 3 + 2] = c2;
    *(int2*)(rr + s * 2) = *(const int2*)(span_ranges + row * 2);
  }
}

// ---------------------------------------------------------------------------
// Kernel 4 (MFMA pairs): one wave per (b, 16x16 tile). Hot loop is pure
// loads + MFMA: 4 x dwordx4 + 3 x mfma_f32_16x16x32_bf16 per K=32 step.
// Epilogue: +aterm+bterm, sigmoid -> softmax over C=3, write probs + ranges.
__global__ __launch_bounds__(256) void k_pairs(const short* __restrict__ Xbf,
                                               const short* __restrict__ Ybf,
                                               const float* __restrict__ aterm,
                                               const float* __restrict__ bterm,
                                               const int* __restrict__ rr,
                                               float* __restrict__ out_probs,
                                               float4* __restrict__ out_ranges) {
  int lane = threadIdx.x & 63;
  int w = blockIdx.x * 4 + (threadIdx.x >> 6);  // 0..799
  int b = w / 100;
  int t = w - b * 100;
  int ti = t / 10;            // i-tile (rows; A side = Y)
  int tj = t - ti * 10;       // j-tile (cols; B side = X)
  int quad = lane >> 4;
  int l16 = lane & 15;

  size_t oa = ((size_t)(b * M_ + ti * 16 + l16)) * D_ + quad * 8;
  size_t ob = ((size_t)(b * M_ + tj * 16 + l16)) * D_ + quad * 8;

  const short* ah0 = Ybf + 0 * BMD_ + oa;
  const short* ah1 = Ybf + 1 * BMD_ + oa;
  const short* ah2 = Ybf + 2 * BMD_ + oa;
  const short* bhp = Xbf + ob;

  floatx4 acc0 = {0.f, 0.f, 0.f, 0.f};
  floatx4 acc1 = {0.f, 0.f, 0.f, 0.f};
  floatx4 acc2 = {0.f, 0.f, 0.f, 0.f};

#pragma unroll 6
  for (int k = 0; k < D_; k += 32) {
    short8 bh = *(const short8*)(bhp + k);
    short8 h0 = *(const short8*)(ah0 + k);
    short8 h1 = *(const short8*)(ah1 + k);
    short8 h2 = *(const short8*)(ah2 + k);
    acc0 = __builtin_amdgcn_mfma_f32_16x16x32_bf16(h0, bh, acc0, 0, 0, 0);
    acc1 = __builtin_amdgcn_mfma_f32_16x16x32_bf16(h1, bh, acc1, 0, 0, 0);
    acc2 = __builtin_amdgcn_mfma_f32_16x16x32_bf16(h2, bh, acc2, 0, 0, 0);
  }

  // Epilogue. C/D layout: col = lane&15 (j), row = quad*4 + reg (i).
  const float* at = aterm + (size_t)(b * M_) * 3;
  const float* bt = bterm + (size_t)(b * M_) * 3;
  const int* rrb = rr + (size_t)(b * M_) * 2;
  int j = tj * 16 + l16;
  float bj0 = bt[j * 3 + 0], bj1 = bt[j * 3 + 1], bj2 = bt[j * 3 + 2];
  int rj0 = rrb[j * 2 + 0], rj1 = rrb[j * 2 + 1];

#pragma unroll
  for (int r = 0; r < 4; ++r) {
    int i = ti * 16 + quad * 4 + r;
    if (i == j) continue;
    float l0 = acc0[r] + at[i * 3 + 0] + bj0;
    float l1 = acc1[r] + at[i * 3 + 1] + bj1;
    float l2 = acc2[r] + at[i * 3 + 2] + bj2;
    float s0 = 1.0f / (1.0f + expf(-l0));
    float s1 = 1.0f / (1.0f + expf(-l1));
    float s2 = 1.0f / (1.0f + expf(-l2));
    float e0 = expf(s0), e1 = expf(s1), e2 = expf(s2);
    float inv = 1.0f / (e0 + e1 + e2);
    int jj = j - (j > i ? 1 : 0);
    size_t p = (size_t)b * PAIRS_ + (size_t)i * (M_ - 1) + jj;
    out_probs[p * 3 + 0] = e0 * inv;
    out_probs[p * 3 + 1] = e1 * inv;
    out_probs[p * 3 + 2] = e2 * inv;
    float4 rg;
    rg.x = (float)rrb[i * 2 + 0];
    rg.y = (float)rrb[i * 2 + 1];
    rg.z = (float)rj0;
    rg.w = (float)rj1;
    out_ranges[p] = rg;
  }
}

// ---------------------------------------------------------------------------
extern "C" void kernel_launch(void* const* d_in, const int* in_sizes, int n_in,
                              void* d_out, int out_size, void* d_ws, size_t ws_size,
                              hipStream_t stream) {
  const float* x = (const float*)d_in[0];
  const float* w_span = (const float*)d_in[1];
  // d_in[2] = b_span: constant shift, irrelevant to the ranking -> unused.
  const float* w_pair = (const float*)d_in[3];
  const float* b_pair = (const float*)d_in[4];
  const int* span_ranges = (const int*)d_in[5];

  char* ws = (char*)d_ws;
  double* z = (double*)ws;
  int* pos = (int*)(ws + 25600);
  float* aterm = (float*)(ws + 30720);
  float* bterm = (float*)(ws + 46080);
  int* rr = (int*)(ws + 61440);
  short* Xbf = (short*)(ws + 71680);
  short* Ybf = (short*)(ws + 2037760);

  float* out = (float*)d_out;
  float* out_probs = out;                                         // B*P*3 floats
  float4* out_ranges = (float4*)(out + (size_t)B_ * PAIRS_ * 3);  // B*P*4 floats

  k_span<<<(B_ * N_) / 4, 256, 0, stream>>>(x, w_span, z);
  k_rank<<<B_, 256, 0, stream>>>(z, pos);
  k_prep_ranked<<<(B_ * M_) / 4, 256, 0, stream>>>(x, w_pair, b_pair, pos,
                                                   span_ranges, aterm, bterm,
                                                   rr, Xbf, Ybf);
  k_pairs<<<(B_ * 100) / 4, 256, 0, stream>>>(Xbf, Ybf, aterm, bterm, rr,
                                              out_probs, out_ranges);
}